// Round 15
// baseline (4238.264 us; speedup 1.0000x reference)
//
#include <hip/hip_runtime.h>
#include <hip/hip_fp16.h>
#include <math.h>

#define B_  64
#define S_  512
#define E_  300
#define H_  256
#define G4_ 1024
#define T_  22
#define M_  (B_*S_)
#define C_  16              // LSTM time chunk
#define NCH (S_/C_)         // 32 chunks
#define CROWS (B_*C_)       // 1024 rows per chunk per dir
#define START_ (T_-2)
#define STOP_  (T_-1)

__device__ __forceinline__ float sigf(float x){ return 1.f/(1.f+expf(-x)); }

// w_hh [1024,256] -> wT16 [1024 col][256 k] fp16, col = 4*j + gate
__global__ __launch_bounds__(256) void wtr16_kernel(const float* __restrict__ whh, __half* __restrict__ wT){
  int tid = blockIdx.x*256 + threadIdx.x;
  if (tid >= H_*G4_) return;
  int col = tid >> 8, k = tid & 255;
  int j = col >> 2, gi = col & 3;
  wT[tid] = __float2half(whh[(size_t)(gi*H_ + j)*H_ + k]);
}

struct __align__(16) TileSmem {
  float As[16][68];
  float Bs[16][68];
  int   widx[64];
  float wmsk[64];
};

struct __align__(16) RecSmem {
  __half w[128][268];        // 68608 B
  float  hp[4][256];         // 4096 B
  float  psum[2][4][32][5];  // 5120 B  [ks][gi][jl][b-pad5]
  float  gbuf[4][4][32];     // 2048 B  [b][gi][jl]
};                            // total 79,872 B -> 2 blocks/CU

union SmemU { RecSmem r; TileSmem t; };

// 64x64 tile GEMM body on 256 logical threads.
__device__ __forceinline__ void gemm_tile_body(
    TileSmem& sm, int tid,
    const float* __restrict__ A,
    const int* __restrict__ word, const int* __restrict__ maskp, const float* __restrict__ emb,
    const float* __restrict__ W, const float* __restrict__ bias,
    float* __restrict__ C, int K, int N, int gather, int t0, int chunkC,
    int row0, int col0) {
  const int tn = tid & 15, tm = tid >> 4;
  if (gather) {
    if (tid < 64) {
      int r  = row0 + tid;
      int b  = r / chunkC;
      int tl = r % chunkC;
      int wr = b*S_ + t0 + tl;
      sm.widx[tid] = word[wr];
      sm.wmsk[tid] = (float)maskp[wr];
    }
    __syncthreads();
  }
  float acc[4][4];
  #pragma unroll
  for (int i=0;i<4;i++)
    #pragma unroll
    for (int j=0;j<4;j++) acc[i][j]=0.f;

  for (int k0 = 0; k0 < K; k0 += 16) {
    #pragma unroll
    for (int i = 0; i < 4; ++i) {
      const int li = tid + (i<<8);
      const int m  = li >> 4, kk = li & 15;
      const int kg = k0 + kk;
      float av = 0.f;
      if (kg < K) {
        if (gather) av = emb[(size_t)sm.widx[m]*K + kg] * sm.wmsk[m];
        else        av = A[(size_t)(row0+m)*K + kg];
      }
      sm.As[kk][m] = av;
      const int nc = col0 + m;
      sm.Bs[kk][m] = (kg < K && nc < N) ? W[(size_t)nc*K + kg] : 0.f;
    }
    __syncthreads();
    #pragma unroll
    for (int kk = 0; kk < 16; ++kk) {
      const float4 a = *(const float4*)&sm.As[kk][tm<<2];
      const float4 b = *(const float4*)&sm.Bs[kk][tn<<2];
      acc[0][0]=fmaf(a.x,b.x,acc[0][0]); acc[0][1]=fmaf(a.x,b.y,acc[0][1]);
      acc[0][2]=fmaf(a.x,b.z,acc[0][2]); acc[0][3]=fmaf(a.x,b.w,acc[0][3]);
      acc[1][0]=fmaf(a.y,b.x,acc[1][0]); acc[1][1]=fmaf(a.y,b.y,acc[1][1]);
      acc[1][2]=fmaf(a.y,b.z,acc[1][2]); acc[1][3]=fmaf(a.y,b.w,acc[1][3]);
      acc[2][0]=fmaf(a.z,b.x,acc[2][0]); acc[2][1]=fmaf(a.z,b.y,acc[2][1]);
      acc[2][2]=fmaf(a.z,b.z,acc[2][2]); acc[2][3]=fmaf(a.z,b.w,acc[2][3]);
      acc[3][0]=fmaf(a.w,b.x,acc[3][0]); acc[3][1]=fmaf(a.w,b.y,acc[3][1]);
      acc[3][2]=fmaf(a.w,b.z,acc[3][2]); acc[3][3]=fmaf(a.w,b.w,acc[3][3]);
    }
    __syncthreads();
  }
  #pragma unroll
  for (int i=0;i<4;i++){
    const int r = row0 + (tm<<2) + i;
    #pragma unroll
    for (int j=0;j<4;j++){
      const int c = col0 + (tn<<2) + j;
      if (c < N) C[(size_t)r*N + c] = acc[i][j] + bias[c];
    }
  }
}

// standalone gates GEMM for chunk 0
__global__ __launch_bounds__(256) void gemm_gates(
    const int* __restrict__ word, const int* __restrict__ maskp, const float* __restrict__ emb,
    const float* __restrict__ w_ih_f, const float* __restrict__ b_f,
    const float* __restrict__ w_ih_b, const float* __restrict__ b_b,
    float* __restrict__ gout, int t0f, int t0b) {
  __shared__ TileSmem sm;
  const int dir = blockIdx.z;
  gemm_tile_body(sm, threadIdx.x, nullptr, word, maskp, emb,
                 dir ? w_ih_b : w_ih_f, dir ? b_b : b_f,
                 gout + (size_t)dir * CROWS * G4_, E_, G4_, 1,
                 dir ? t0b : t0f, C_, blockIdx.x << 6, blockIdx.y << 6);
}

// Fused full highway + emissions: grid (M/32) x 256 thr. Block owns 32 rows.
// Phase 1: proj GEMM (XOR-swizzled Bs, conflict-free), highway h2 in place.
// Phase 2: h2 stashed in LDS (stride 516 -> conflict-free), emissions
//          emit[r][tt] = sum_k h2[r][k]*outW[tt][k] + outb[tt], k ascending
//          (bit-identical order to the old standalone emissions GEMM).
__global__ __launch_bounds__(256, 4) void gemm_hw_full(
    float* __restrict__ h, const float* __restrict__ hwW, const float* __restrict__ hwb,
    const float* __restrict__ outW, const float* __restrict__ outb,
    float* __restrict__ emit) {
  __shared__ __align__(16) float As[16][36];     // [kk][row]
  __shared__ __align__(16) union {
    float Bs[16][1024];                          // [kk][phys col], XOR-swizzled
    float h2s[32][516];                          // [row][k] stashed h2 (+4 pad)
  } u_;
  const int tid = threadIdx.x;
  const int cg  = tid & 63;          // col lane: logical cols cg + 64u
  const int rg  = tid >> 6;          // row-group: 8 rows
  const int row0 = blockIdx.x << 5;
  const int r0 = rg << 3;
  float an[8][8], ag[8][8];
  #pragma unroll
  for (int i=0;i<8;++i)
    #pragma unroll
    for (int uu=0;uu<8;++uu){ an[i][uu]=0.f; ag[i][uu]=0.f; }

  for (int k0 = 0; k0 < 512; k0 += 16) {
    // stage As: 32 rows x 16 k = 512 floats
    #pragma unroll
    for (int it = 0; it < 2; ++it) {
      const int e = tid + (it << 8);     // 0..511
      const int rr = e >> 4, kk = e & 15;
      As[kk][rr] = h[(size_t)(row0 + rr)*512 + k0 + kk];
    }
    // stage Bs: 1024 W-rows x 16 k = 4096 float4, col-swizzled by (row>>2)
    #pragma unroll
    for (int it = 0; it < 16; ++it) {
      const int e = tid + (it << 8);     // 0..4095
      const int c  = e >> 2;             // logical col 0..1023
      const int q  = e & 3;              // kq = q*4
      const int kq = q << 2;
      const int cx = c ^ (q << 3);       // physical col
      const float4 v = *(const float4*)&hwW[(size_t)c*512 + k0 + kq];
      u_.Bs[kq+0][cx] = v.x; u_.Bs[kq+1][cx] = v.y; u_.Bs[kq+2][cx] = v.z; u_.Bs[kq+3][cx] = v.w;
    }
    __syncthreads();
    #pragma unroll 4
    for (int kk = 0; kk < 16; ++kk) {
      const float4 a0 = *(const float4*)&As[kk][r0];
      const float4 a1 = *(const float4*)&As[kk][r0+4];
      const float ar[8] = {a0.x,a0.y,a0.z,a0.w,a1.x,a1.y,a1.z,a1.w};
      const int cgx = cg ^ ((kk >> 2) << 3);   // unswizzled lane base for this kk
      float bn[8], bg[8];
      #pragma unroll
      for (int uu = 0; uu < 8; ++uu) {
        bn[uu] = u_.Bs[kk][cgx + (uu<<6)];
        bg[uu] = u_.Bs[kk][512 + cgx + (uu<<6)];
      }
      #pragma unroll
      for (int i = 0; i < 8; ++i)
        #pragma unroll
        for (int uu = 0; uu < 8; ++uu) {
          an[i][uu] = fmaf(ar[i], bn[uu], an[i][uu]);
          ag[i][uu] = fmaf(ar[i], bg[uu], ag[i][uu]);
        }
    }
    __syncthreads();
  }
  // phase-1 epilogue: h2 = g*h + (1-g)*relu(nl), in place + LDS stash
  #pragma unroll
  for (int uu = 0; uu < 8; ++uu) {
    const int c = cg + (uu<<6);
    const float bn_ = hwb[c];
    const float bg_ = hwb[512 + c];
    #pragma unroll
    for (int i = 0; i < 8; ++i) {
      const size_t off = (size_t)(row0 + r0 + i)*512 + c;
      const float nl = an[i][uu] + bn_;
      const float gt = ag[i][uu] + bg_;
      const float hv = h[off];
      const float gv = sigf(gt);
      const float h2 = gv*hv + (1.f-gv)*fmaxf(nl, 0.f);
      h[off] = h2;
      u_.h2s[r0 + i][c] = h2;
    }
  }
  __syncthreads();
  // phase 2: emissions for these 32 rows. thread = (row er, tag-group eg)
  const int er = tid >> 3;           // 0..31
  const int eg = tid & 7;            // 0..7 -> tags eg, eg+8, eg+16
  for (int tt = eg; tt < T_; tt += 8) {
    const float* wrow = &outW[(size_t)tt*512];
    float acc = 0.f;
    for (int k = 0; k < 512; k += 4) {
      const float4 hv = *(const float4*)&u_.h2s[er][k];
      const float4 wv = *(const float4*)&wrow[k];
      acc = fmaf(hv.x, wv.x, acc);
      acc = fmaf(hv.y, wv.y, acc);
      acc = fmaf(hv.z, wv.z, acc);
      acc = fmaf(hv.w, wv.w, acc);
    }
    emit[(size_t)(row0 + er)*T_ + tt] = acc + outb[tt];
  }
}

// Fused: bids [0,256) = recurrence (fp16 weights in LDS, fence-free u64-tag exchange);
//        bids [256,512) = next chunk's gates GEMM (2 tiles each), co-resident per CU.
__global__ __launch_bounds__(256) void lstm_mega(
    const float* __restrict__ gcur, float* __restrict__ gnext,
    const int* __restrict__ word, const int* __restrict__ maskp, const float* __restrict__ emb,
    const float* __restrict__ w_ih_f, const float* __restrict__ b_f,
    const float* __restrict__ w_ih_b, const float* __restrict__ b_b,
    const __half* __restrict__ wT16,
    float* __restrict__ h_bi, float* __restrict__ stH, float* __restrict__ stC,
    unsigned long long* __restrict__ hx,
    int t0f, int t0b, int n0f, int n0b, int ebase, int first) {
  __shared__ SmemU sm;
  const int bid = blockIdx.x;
  const int tid = threadIdx.x;

  if (bid >= 256) {
    if (n0f < 0) return;
    #pragma unroll 1
    for (int hfl = 0; hfl < 2; ++hfl) {
      const int tile = (bid - 256)*2 + hfl;      // 0..511
      const int dirg = tile >> 8;
      const int tt   = tile & 255;
      gemm_tile_body(sm.t, tid, nullptr, word, maskp, emb,
                     dirg ? w_ih_b : w_ih_f, dirg ? b_b : b_f,
                     gnext + (size_t)dirg * CROWS * G4_, E_, G4_, 1,
                     dirg ? n0b : n0f, C_, (tt & 15) << 6, (tt >> 4) << 6);
      __syncthreads();
    }
    return;
  }

  // ---- recurrence role ----
  const int dir = bid & 1;
  const int cs  = (bid >> 1) & 7;        // col-slice: 32 h-cols
  const int bq  = bid >> 4;              // batch-quad 0..15
  const int gidx = dir*16 + bq;          // group 0..31 (8 cs-blocks each)
  const float*  __restrict__ g    = gcur + (size_t)dir * CROWS * G4_;
  const __half* __restrict__ wsrc = wT16 + (size_t)dir * (G4_*H_);
  const int hoff = dir ? H_ : 0;

  // stage fp16 weight slice: cols [cs*128, +128) x 256 k
  for (int it = 0; it < 32; ++it) {
    const int idx = tid + (it << 8);     // 0..8191
    const int lc = idx >> 6;             // 0..127
    const int k0 = (idx & 63) << 2;      // 0..252
    const uint2 u = *(const uint2*)&wsrc[(size_t)(cs*128 + lc)*256 + k0];
    *(uint2*)&sm.r.w[lc][k0] = u;
  }
  for (int it = 0; it < 4; ++it) {
    const int idx = tid + (it << 8);
    const int b = idx >> 8, col = idx & 255;
    sm.r.hp[b][col] = first ? 0.f : stH[((size_t)(dir*B_ + bq*4 + b))*H_ + col];
  }
  const int ab  = tid >> 5;              // activation batch (tid<128)
  const int ajl = tid & 31;              // activation h-col-local
  float creg = 0.f;
  if (!first && tid < 128)
    creg = stC[((size_t)(dir*B_ + bq*4 + ab))*H_ + cs*32 + ajl];
  __syncthreads();

  const int ks = tid >> 7;               // k-half 0..1
  const int lc = tid & 127;              // gate-col-local
  const int gi = lc & 3, jl = lc >> 2;
  const int kb = ks << 7;
  const int gb0  = tid >> 7;             // gate prefetch mapping
  const int grem = tid & 127;
  const int ggi = grem >> 5, gjl = grem & 31;
  const size_t gcol = (size_t)ggi*256 + cs*32 + gjl;

  for (int sl = 0; sl < C_; ++sl) {
    const int t  = dir ? (t0b + C_-1-sl) : (t0f + sl);
    const int tl = dir ? (C_-1-sl) : sl;
    const float gv0 = g[(size_t)((bq*4 + gb0    )*C_ + tl)*G4_ + gcol];
    const float gv1 = g[(size_t)((bq*4 + gb0 + 2)*C_ + tl)*G4_ + gcol];

    float acc0=0.f, acc1=0.f, acc2=0.f, acc3=0.f;
    #pragma unroll 8
    for (int kq = 0; kq < 32; ++kq) {
      const int k0 = kb + (kq << 2);
      const uint2 u = *(const uint2*)&sm.r.w[lc][k0];
      __half2 p01, p23;
      *(unsigned*)&p01 = u.x; *(unsigned*)&p23 = u.y;
      const float2 f01 = __half22float2(p01);
      const float2 f23 = __half22float2(p23);
      const float4 h0 = *(const float4*)&sm.r.hp[0][k0];
      const float4 h1 = *(const float4*)&sm.r.hp[1][k0];
      const float4 h2 = *(const float4*)&sm.r.hp[2][k0];
      const float4 h3 = *(const float4*)&sm.r.hp[3][k0];
      acc0 = fmaf(f01.x,h0.x,fmaf(f01.y,h0.y,fmaf(f23.x,h0.z,fmaf(f23.y,h0.w,acc0))));
      acc1 = fmaf(f01.x,h1.x,fmaf(f01.y,h1.y,fmaf(f23.x,h1.z,fmaf(f23.y,h1.w,acc1))));
      acc2 = fmaf(f01.x,h2.x,fmaf(f01.y,h2.y,fmaf(f23.x,h2.z,fmaf(f23.y,h2.w,acc2))));
      acc3 = fmaf(f01.x,h3.x,fmaf(f01.y,h3.y,fmaf(f23.x,h3.z,fmaf(f23.y,h3.w,acc3))));
    }
    sm.r.psum[ks][gi][jl][0]=acc0; sm.r.psum[ks][gi][jl][1]=acc1;
    sm.r.psum[ks][gi][jl][2]=acc2; sm.r.psum[ks][gi][jl][3]=acc3;
    sm.r.gbuf[gb0    ][ggi][gjl] = gv0;
    sm.r.gbuf[gb0 + 2][ggi][gjl] = gv1;
    __syncthreads();

    const int e = ebase + sl;
    const int par = e & 1;
    const unsigned tag = (unsigned)(e + 1);
    if (tid < 128) {
      const float pre0 = sm.r.gbuf[ab][0][ajl] + sm.r.psum[0][0][ajl][ab] + sm.r.psum[1][0][ajl][ab];
      const float pre1 = sm.r.gbuf[ab][1][ajl] + sm.r.psum[0][1][ajl][ab] + sm.r.psum[1][1][ajl][ab];
      const float pre2 = sm.r.gbuf[ab][2][ajl] + sm.r.psum[0][2][ajl][ab] + sm.r.psum[1][2][ajl][ab];
      const float pre3 = sm.r.gbuf[ab][3][ajl] + sm.r.psum[0][3][ajl][ab] + sm.r.psum[1][3][ajl][ab];
      const float iv = sigf(pre0), fv = sigf(pre1);
      const float zv = tanhf(pre2), ov = sigf(pre3);
      creg = fv*creg + iv*zv;
      const float hn = ov * tanhf(creg);
      h_bi[((size_t)((bq*4+ab)*S_ + t))*(2*H_) + hoff + cs*32 + ajl] = hn;
      if (sl < C_-1) {
        const unsigned long long pk =
            ((unsigned long long)tag << 32) | (unsigned long long)__float_as_uint(hn);
        __hip_atomic_store(&hx[(((size_t)par*32 + gidx)*4 + ab)*256 + cs*32 + ajl], pk,
                           __ATOMIC_RELAXED, __HIP_MEMORY_SCOPE_AGENT);
      } else {
        stH[((size_t)(dir*B_ + bq*4 + ab))*H_ + cs*32 + ajl] = hn;
        stC[((size_t)(dir*B_ + bq*4 + ab))*H_ + cs*32 + ajl] = creg;
      }
    }
    if (sl == C_-1) break;

    // fence-free gather: poll u64 (tag|value), 4 in flight per thread
    {
      const unsigned long long* hb = &hx[((size_t)par*32 + gidx) << 10];
      float r0,r1,r2,r3;
      bool d0=false,d1=false,d2=false,d3=false;
      for (;;) {
        if (!d0) { unsigned long long v = __hip_atomic_load(hb + tid,       __ATOMIC_RELAXED, __HIP_MEMORY_SCOPE_AGENT);
                   if ((unsigned)(v>>32) == tag) { r0 = __uint_as_float((unsigned)v); d0 = true; } }
        if (!d1) { unsigned long long v = __hip_atomic_load(hb + 256 + tid, __ATOMIC_RELAXED, __HIP_MEMORY_SCOPE_AGENT);
                   if ((unsigned)(v>>32) == tag) { r1 = __uint_as_float((unsigned)v); d1 = true; } }
        if (!d2) { unsigned long long v = __hip_atomic_load(hb + 512 + tid, __ATOMIC_RELAXED, __HIP_MEMORY_SCOPE_AGENT);
                   if ((unsigned)(v>>32) == tag) { r2 = __uint_as_float((unsigned)v); d2 = true; } }
        if (!d3) { unsigned long long v = __hip_atomic_load(hb + 768 + tid, __ATOMIC_RELAXED, __HIP_MEMORY_SCOPE_AGENT);
                   if ((unsigned)(v>>32) == tag) { r3 = __uint_as_float((unsigned)v); d3 = true; } }
        if (d0 && d1 && d2 && d3) break;
        __builtin_amdgcn_s_sleep(1);
      }
      sm.r.hp[0][tid] = r0; sm.r.hp[1][tid] = r1;
      sm.r.hp[2][tid] = r2; sm.r.hp[3][tid] = r3;
    }
    __syncthreads();
  }
}

__global__ __launch_bounds__(256) void gold_kernel(
    const int* __restrict__ labels, const int* __restrict__ maskp,
    const float* __restrict__ emitp, const float* __restrict__ trans, double* __restrict__ gold) {
  const int b = blockIdx.x; const int tid = threadIdx.x;
  double acc = 0.0; int len = 0;
  for (int t = tid; t < S_; t += 256) {
    int mk = maskp[b*S_ + t];
    len += mk;
    if (mk) {
      int lab  = labels[b*S_ + t];
      int prev = (t==0) ? START_ : labels[b*S_ + t - 1];
      acc += (double)trans[prev*T_ + lab] + (double)emitp[((size_t)b*S_ + t)*T_ + lab];
    }
  }
  __shared__ double sacc[256]; __shared__ int slen[256];
  sacc[tid]=acc; slen[tid]=len; __syncthreads();
  for (int s=128; s>0; s>>=1){ if (tid<s){ sacc[tid]+=sacc[tid+s]; slen[tid]+=slen[tid+s]; } __syncthreads(); }
  if (tid==0){
    int L = slen[0];
    int last = labels[b*S_ + L - 1];
    gold[b] = sacc[0] + (double)trans[last*T_ + STOP_];
  }
}

// Register-resident CRF-forward (role 0) + Viterbi (role 1). One wave per (batch, role).
__global__ __launch_bounds__(64) void crf_vit_kernel(
    const float* __restrict__ emitp, const float* __restrict__ trans,
    const int* __restrict__ maskp, double* __restrict__ fwd, float* __restrict__ out_tags) {
  const int b = blockIdx.x;
  const int role = blockIdx.y;
  const int lane = threadIdx.x;
  const int k = lane & 31, p = lane >> 5;
  const int kk = (k < T_) ? k : 0;

  __shared__ float trs[T_*T_];
  for (int i = lane; i < T_*T_; i += 64) trs[i] = trans[i];
  __syncthreads();

  // preload this lane's trans column: sources j = p*11+u -> target kk
  float trreg[11];
  #pragma unroll
  for (int u = 0; u < 11; ++u) trreg[u] = trs[(p*11 + u)*T_ + kk];

  if (role == 0) {
    double al_r = 0.0;
    if (lane < T_) al_r = (double)emitp[(size_t)b*S_*T_ + lane] + (double)trs[START_*T_ + lane];
    float ce = emitp[((size_t)b*S_ + 1)*T_ + kk];
    int   cm = maskp[b*S_ + 1];
    for (int t = 1; t < S_; ++t) {
      float ne = 0.f; int nm = 0;
      if (t+1 < S_) { ne = emitp[((size_t)b*S_ + t + 1)*T_ + kk]; nm = maskp[b*S_ + t + 1]; }
      double tj[11];
      #pragma unroll
      for (int u = 0; u < 11; ++u)
        tj[u] = __shfl(al_r, p*11 + u) + (double)trreg[u];
      double m = tj[0];
      #pragma unroll
      for (int u = 1; u < 11; ++u) m = fmax(m, tj[u]);
      m = fmax(m, __shfl_xor(m, 32));
      float s = 0.f;
      #pragma unroll
      for (int u = 0; u < 11; ++u) s += __expf((float)(tj[u] - m));
      s += __shfl_xor(s, 32);
      const double nv = m + (double)__logf(s) + (double)ce;
      if (cm && lane < T_) al_r = nv;
      ce = ne; cm = nm;
    }
    if (lane < T_) al_r += (double)trs[lane*T_ + STOP_];
    // wave-reduce logsumexp over lanes 0..21
    double mx = (lane < T_) ? al_r : -1e300;
    #pragma unroll
    for (int o = 32; o > 0; o >>= 1) mx = fmax(mx, __shfl_xor(mx, o));
    double sv = (lane < T_) ? exp(al_r - mx) : 0.0;
    #pragma unroll
    for (int o = 32; o > 0; o >>= 1) sv += __shfl_xor(sv, o);
    if (lane == 0) fwd[b] = mx + log(sv);
  } else {
    __shared__ unsigned char bp[S_][T_];
    __shared__ int msk[S_];
    double dl_r = 0.0;
    if (lane < T_) dl_r = (double)emitp[(size_t)b*S_*T_ + lane] + (double)trs[START_*T_ + lane];
    if (lane == 0) msk[0] = maskp[b*S_];
    float ce = emitp[((size_t)b*S_ + 1)*T_ + kk];
    int   cm = maskp[b*S_ + 1];
    for (int t = 1; t < S_; ++t) {
      float ne = 0.f; int nm = 0;
      if (t+1 < S_) { ne = emitp[((size_t)b*S_ + t + 1)*T_ + kk]; nm = maskp[b*S_ + t + 1]; }
      double best = __shfl(dl_r, p*11) + (double)trreg[0];
      int arg = p*11;
      #pragma unroll
      for (int u = 1; u < 11; ++u) {
        const double sc = __shfl(dl_r, p*11 + u) + (double)trreg[u];
        if (sc > best) { best = sc; arg = p*11 + u; }
      }
      const double ob = __shfl_xor(best, 32);
      const int    oa = __shfl_xor(arg, 32);
      if (p == 0 && ob > best) { best = ob; arg = oa; }   // strict >: lower j wins ties
      if (p == 0 && k < T_) {
        if (cm) { dl_r = best + (double)ce; bp[t][k] = (unsigned char)arg; }
        else    { bp[t][k] = (unsigned char)k; }
      }
      if (lane == 0) msk[t] = cm;
      ce = ne; cm = nm;
    }
    __syncthreads();
    // wave-uniform final argmax over j=0..21 (lowest j wins ties), all lanes active
    double sc = (lane < T_) ? dl_r + (double)trs[lane*T_ + STOP_] : -1e300;
    int cur = (lane < T_) ? lane : 0x7fffffff;
    #pragma unroll
    for (int o = 32; o > 0; o >>= 1) {
      const double osc = __shfl_xor(sc, o);
      const int    oid = __shfl_xor(cur, o);
      if (osc > sc || (osc == sc && oid < cur)) { sc = osc; cur = oid; }
    }
    if (lane == 0) {
      for (int t = S_-1; ; --t) {
        out_tags[b*S_ + t] = (float)(cur * msk[t]);
        if (t == 0) break;
        cur = bp[t][cur];
      }
    }
  }
}

__global__ void finalize_kernel(const double* __restrict__ fwd, const double* __restrict__ gold, float* __restrict__ out){
  if (threadIdx.x == 0 && blockIdx.x == 0) {
    double s = 0.0, g = 0.0;
    for (int b = 0; b < B_; ++b) { s += fwd[b]; g += gold[b]; }
    out[0] = (float)((s - g) / (double)B_);
  }
}

extern "C" void kernel_launch(void* const* d_in, const int* in_sizes, int n_in,
                              void* d_out, int out_size, void* d_ws, size_t ws_size,
                              hipStream_t stream) {
  const int*   word   = (const int*)d_in[0];
  const int*   maskp  = (const int*)d_in[1];
  const int*   labels = (const int*)d_in[2];
  const float* emb    = (const float*)d_in[3];
  const float* w_ih_f = (const float*)d_in[4];
  const float* w_hh_f = (const float*)d_in[5];
  const float* b_f    = (const float*)d_in[6];
  const float* w_ih_b = (const float*)d_in[7];
  const float* w_hh_b = (const float*)d_in[8];
  const float* b_b    = (const float*)d_in[9];
  const float* hw_W   = (const float*)d_in[10];
  const float* hw_b   = (const float*)d_in[11];
  const float* out_W  = (const float*)d_in[12];
  const float* out_b  = (const float*)d_in[13];
  const float* trans  = (const float*)d_in[14];
  float* out = (float*)d_out;

  // workspace layout (~88.6 MB)
  float* h_bi  = (float*)d_ws;                          // [32768,512] -> h2 in place
  float* buf0  = h_bi + 16777216ULL;                    // [2,1024,1024] gates ping
  float* buf1  = buf0 + 2097152ULL;                     // [2,1024,1024] gates pong
  __half* wT16 = (__half*)(buf1 + 2097152ULL);          // [2][1024 col][256 k] fp16
  float* emitp = (float*)(wT16 + 524288ULL);            // [32768,22]
  float* stH   = emitp + 720896ULL;                     // [2,64,256]
  float* stC   = stH + 32768ULL;                        // [2,64,256]
  unsigned long long* hx = (unsigned long long*)(stC + 32768ULL);  // [2 par][32 g][4 b][256]
  double* fwdp = (double*)(hx + 65536ULL);              // [64]
  double* goldp = fwdp + 64;                            // [64]

  hipMemsetAsync(hx, 0, 65536ULL * 8, stream);          // clear tags (replay safety)

  wtr16_kernel<<<1024, 256, 0, stream>>>(w_hh_f, wT16);
  wtr16_kernel<<<1024, 256, 0, stream>>>(w_hh_b, wT16 + 262144ULL);

  // chunk 0 gates -> buf0
  gemm_gates<<<dim3(CROWS/64, 16, 2), 256, 0, stream>>>(
      word, maskp, emb, w_ih_f, b_f, w_ih_b, b_b, buf0, 0, S_ - C_);

  // fused recurrence + next-chunk gates
  for (int i = 0; i < NCH; ++i) {
    const int t0f = i * C_;
    const int t0b = S_ - (i + 1) * C_;
    const int n0f = (i < NCH-1) ? (i + 1) * C_ : -1;
    const int n0b = S_ - (i + 2) * C_;
    float* gcur = (i & 1) ? buf1 : buf0;
    float* gnext = (i & 1) ? buf0 : buf1;
    lstm_mega<<<512, 256, 0, stream>>>(
        gcur, gnext, word, maskp, emb, w_ih_f, b_f, w_ih_b, b_b,
        wT16, h_bi, stH, stC, hx, t0f, t0b, n0f, n0b, i*(C_-1), (i == 0) ? 1 : 0);
  }

  // fused highway + emissions (h2 in place on h_bi; emit written directly)
  gemm_hw_full<<<M_/32, 256, 0, stream>>>(h_bi, hw_W, hw_b, out_W, out_b, emitp);

  // CRF
  gold_kernel<<<64, 256, 0, stream>>>(labels, maskp, emitp, trans, goldp);
  crf_vit_kernel<<<dim3(64, 2), 64, 0, stream>>>(emitp, trans, maskp, fwdp, out + 1);
  finalize_kernel<<<1, 64, 0, stream>>>(fwdp, goldp, out);
}

// Round 16
// 4008.439 us; speedup vs baseline: 1.0573x; 1.0573x over previous
//
#include <hip/hip_runtime.h>
#include <hip/hip_fp16.h>
#include <math.h>

#define B_  64
#define S_  512
#define E_  300
#define H_  256
#define G4_ 1024
#define T_  22
#define M_  (B_*S_)
#define C_  16              // LSTM time chunk
#define NCH (S_/C_)         // 32 chunks
#define CROWS (B_*C_)       // 1024 rows per chunk per dir
#define START_ (T_-2)
#define STOP_  (T_-1)

__device__ __forceinline__ float sigf(float x){ return 1.f/(1.f+expf(-x)); }

// w_hh [1024,256] -> wT16 [1024 col][256 k] fp16, col = 4*j + gate
__global__ __launch_bounds__(256) void wtr16_kernel(const float* __restrict__ whh, __half* __restrict__ wT){
  int tid = blockIdx.x*256 + threadIdx.x;
  if (tid >= H_*G4_) return;
  int col = tid >> 8, k = tid & 255;
  int j = col >> 2, gi = col & 3;
  wT[tid] = __float2half(whh[(size_t)(gi*H_ + j)*H_ + k]);
}

struct __align__(16) TileSmem {
  float As[16][68];
  float Bs[16][68];
  int   widx[64];
  float wmsk[64];
};

struct __align__(16) RecSmem {
  __half w[128][268];        // 68608 B
  float  hp[4][256];         // 4096 B
  float  psum[2][4][32][5];  // 5120 B  [ks][gi][jl][b-pad5]
  float  gbuf[4][4][32];     // 2048 B  [b][gi][jl]
};                            // total 79,872 B -> 2 blocks/CU

union SmemU { RecSmem r; TileSmem t; };

// 64x64 tile GEMM body on 256 logical threads.
__device__ __forceinline__ void gemm_tile_body(
    TileSmem& sm, int tid,
    const float* __restrict__ A,
    const int* __restrict__ word, const int* __restrict__ maskp, const float* __restrict__ emb,
    const float* __restrict__ W, const float* __restrict__ bias,
    float* __restrict__ C, int K, int N, int gather, int t0, int chunkC,
    int row0, int col0) {
  const int tn = tid & 15, tm = tid >> 4;
  if (gather) {
    if (tid < 64) {
      int r  = row0 + tid;
      int b  = r / chunkC;
      int tl = r % chunkC;
      int wr = b*S_ + t0 + tl;
      sm.widx[tid] = word[wr];
      sm.wmsk[tid] = (float)maskp[wr];
    }
    __syncthreads();
  }
  float acc[4][4];
  #pragma unroll
  for (int i=0;i<4;i++)
    #pragma unroll
    for (int j=0;j<4;j++) acc[i][j]=0.f;

  for (int k0 = 0; k0 < K; k0 += 16) {
    #pragma unroll
    for (int i = 0; i < 4; ++i) {
      const int li = tid + (i<<8);
      const int m  = li >> 4, kk = li & 15;
      const int kg = k0 + kk;
      float av = 0.f;
      if (kg < K) {
        if (gather) av = emb[(size_t)sm.widx[m]*K + kg] * sm.wmsk[m];
        else        av = A[(size_t)(row0+m)*K + kg];
      }
      sm.As[kk][m] = av;
      const int nc = col0 + m;
      sm.Bs[kk][m] = (kg < K && nc < N) ? W[(size_t)nc*K + kg] : 0.f;
    }
    __syncthreads();
    #pragma unroll
    for (int kk = 0; kk < 16; ++kk) {
      const float4 a = *(const float4*)&sm.As[kk][tm<<2];
      const float4 b = *(const float4*)&sm.Bs[kk][tn<<2];
      acc[0][0]=fmaf(a.x,b.x,acc[0][0]); acc[0][1]=fmaf(a.x,b.y,acc[0][1]);
      acc[0][2]=fmaf(a.x,b.z,acc[0][2]); acc[0][3]=fmaf(a.x,b.w,acc[0][3]);
      acc[1][0]=fmaf(a.y,b.x,acc[1][0]); acc[1][1]=fmaf(a.y,b.y,acc[1][1]);
      acc[1][2]=fmaf(a.y,b.z,acc[1][2]); acc[1][3]=fmaf(a.y,b.w,acc[1][3]);
      acc[2][0]=fmaf(a.z,b.x,acc[2][0]); acc[2][1]=fmaf(a.z,b.y,acc[2][1]);
      acc[2][2]=fmaf(a.z,b.z,acc[2][2]); acc[2][3]=fmaf(a.z,b.w,acc[2][3]);
      acc[3][0]=fmaf(a.w,b.x,acc[3][0]); acc[3][1]=fmaf(a.w,b.y,acc[3][1]);
      acc[3][2]=fmaf(a.w,b.z,acc[3][2]); acc[3][3]=fmaf(a.w,b.w,acc[3][3]);
    }
    __syncthreads();
  }
  #pragma unroll
  for (int i=0;i<4;i++){
    const int r = row0 + (tm<<2) + i;
    #pragma unroll
    for (int j=0;j<4;j++){
      const int c = col0 + (tn<<2) + j;
      if (c < N) C[(size_t)r*N + c] = acc[i][j] + bias[c];
    }
  }
}

__global__ __launch_bounds__(256) void gemm_tiled(
    const float* __restrict__ A,
    const int* __restrict__ word, const int* __restrict__ maskp, const float* __restrict__ emb,
    const float* __restrict__ W, const float* __restrict__ bias,
    float* __restrict__ C, int K, int N, int gather, int t0, int chunkC) {
  __shared__ TileSmem sm;
  gemm_tile_body(sm, threadIdx.x, A, word, maskp, emb, W, bias, C, K, N,
                 gather, t0, chunkC, blockIdx.x << 6, blockIdx.y << 6);
}

// standalone gates GEMM for chunk 0
__global__ __launch_bounds__(256) void gemm_gates(
    const int* __restrict__ word, const int* __restrict__ maskp, const float* __restrict__ emb,
    const float* __restrict__ w_ih_f, const float* __restrict__ b_f,
    const float* __restrict__ w_ih_b, const float* __restrict__ b_b,
    float* __restrict__ gout, int t0f, int t0b) {
  __shared__ TileSmem sm;
  const int dir = blockIdx.z;
  gemm_tile_body(sm, threadIdx.x, nullptr, word, maskp, emb,
                 dir ? w_ih_b : w_ih_f, dir ? b_b : b_f,
                 gout + (size_t)dir * CROWS * G4_, E_, G4_, 1,
                 dir ? t0b : t0f, C_, blockIdx.x << 6, blockIdx.y << 6);
}

// Fused full highway: grid (M/32) blocks x 256 thr. Block owns 32 rows x ALL 1024 proj
// cols -> computes nl+gate, applies highway, writes h2 IN PLACE (no proj buffer).
// Bank conflicts removed by row-dependent XOR column swizzle: phys_col = c ^ ((row>>2)<<3).
__global__ __launch_bounds__(256, 4) void gemm_hw_full(
    float* __restrict__ h, const float* __restrict__ hwW, const float* __restrict__ hwb) {
  __shared__ __align__(16) float As[16][36];     // [kk][row]
  __shared__ __align__(16) float Bs[16][1024];   // [kk][phys col], XOR-swizzled
  const int tid = threadIdx.x;
  const int cg  = tid & 63;          // col lane: logical cols cg + 64u
  const int rg  = tid >> 6;          // row-group: 8 rows
  const int row0 = blockIdx.x << 5;
  const int r0 = rg << 3;
  float an[8][8], ag[8][8];
  #pragma unroll
  for (int i=0;i<8;++i)
    #pragma unroll
    for (int u=0;u<8;++u){ an[i][u]=0.f; ag[i][u]=0.f; }

  for (int k0 = 0; k0 < 512; k0 += 16) {
    // stage As: 32 rows x 16 k = 512 floats
    #pragma unroll
    for (int it = 0; it < 2; ++it) {
      const int e = tid + (it << 8);     // 0..511
      const int rr = e >> 4, kk = e & 15;
      As[kk][rr] = h[(size_t)(row0 + rr)*512 + k0 + kk];
    }
    // stage Bs: 1024 W-rows x 16 k = 4096 float4, col-swizzled by (row>>2)
    #pragma unroll
    for (int it = 0; it < 16; ++it) {
      const int e = tid + (it << 8);     // 0..4095
      const int c  = e >> 2;             // logical col 0..1023
      const int q  = e & 3;              // kq = q*4
      const int kq = q << 2;
      const int cx = c ^ (q << 3);       // physical col
      const float4 v = *(const float4*)&hwW[(size_t)c*512 + k0 + kq];
      Bs[kq+0][cx] = v.x; Bs[kq+1][cx] = v.y; Bs[kq+2][cx] = v.z; Bs[kq+3][cx] = v.w;
    }
    __syncthreads();
    #pragma unroll 4
    for (int kk = 0; kk < 16; ++kk) {
      const float4 a0 = *(const float4*)&As[kk][r0];
      const float4 a1 = *(const float4*)&As[kk][r0+4];
      const float ar[8] = {a0.x,a0.y,a0.z,a0.w,a1.x,a1.y,a1.z,a1.w};
      const int cgx = cg ^ ((kk >> 2) << 3);   // unswizzled lane base for this kk
      float bn[8], bg[8];
      #pragma unroll
      for (int u = 0; u < 8; ++u) {
        bn[u] = Bs[kk][cgx + (u<<6)];
        bg[u] = Bs[kk][512 + cgx + (u<<6)];
      }
      #pragma unroll
      for (int i = 0; i < 8; ++i)
        #pragma unroll
        for (int u = 0; u < 8; ++u) {
          an[i][u] = fmaf(ar[i], bn[u], an[i][u]);
          ag[i][u] = fmaf(ar[i], bg[u], ag[i][u]);
        }
    }
    __syncthreads();
  }
  // epilogue: h2 = g*h + (1-g)*relu(nl), in place (each (r,c) owned by one thread)
  #pragma unroll
  for (int u = 0; u < 8; ++u) {
    const int c = cg + (u<<6);
    const float bn_ = hwb[c];
    const float bg_ = hwb[512 + c];
    #pragma unroll
    for (int i = 0; i < 8; ++i) {
      const size_t off = (size_t)(row0 + r0 + i)*512 + c;
      const float nl = an[i][u] + bn_;
      const float gt = ag[i][u] + bg_;
      const float hv = h[off];
      const float gv = sigf(gt);
      h[off] = gv*hv + (1.f-gv)*fmaxf(nl, 0.f);
    }
  }
}

// Fused: bids [0,256) = recurrence (fp16 weights in LDS, fence-free u64-tag exchange);
//        bids [256,512) = next chunk's gates GEMM (2 tiles each), co-resident per CU.
// Recurrence decode: cs = bid>>5, dir/bq = bid&31 -> the 8 cs-blocks of each (dir,bq)
// group have bids congruent mod 8 -> same XCD under round-robin placement, keeping the
// hx exchange XCD-L2-local instead of die-LLC (index permutation only; protocol unchanged).
__global__ __launch_bounds__(256) void lstm_mega(
    const float* __restrict__ gcur, float* __restrict__ gnext,
    const int* __restrict__ word, const int* __restrict__ maskp, const float* __restrict__ emb,
    const float* __restrict__ w_ih_f, const float* __restrict__ b_f,
    const float* __restrict__ w_ih_b, const float* __restrict__ b_b,
    const __half* __restrict__ wT16,
    float* __restrict__ h_bi, float* __restrict__ stH, float* __restrict__ stC,
    unsigned long long* __restrict__ hx,
    int t0f, int t0b, int n0f, int n0b, int ebase, int first) {
  __shared__ SmemU sm;
  const int bid = blockIdx.x;
  const int tid = threadIdx.x;

  if (bid >= 256) {
    if (n0f < 0) return;
    #pragma unroll 1
    for (int hfl = 0; hfl < 2; ++hfl) {
      const int tile = (bid - 256)*2 + hfl;      // 0..511
      const int dirg = tile >> 8;
      const int tt   = tile & 255;
      gemm_tile_body(sm.t, tid, nullptr, word, maskp, emb,
                     dirg ? w_ih_b : w_ih_f, dirg ? b_b : b_f,
                     gnext + (size_t)dirg * CROWS * G4_, E_, G4_, 1,
                     dirg ? n0b : n0f, C_, (tt & 15) << 6, (tt >> 4) << 6);
      __syncthreads();
    }
    return;
  }

  // ---- recurrence role ----
  const int low5 = bid & 31;
  const int dir = low5 >> 4;
  const int bq  = low5 & 15;             // batch-quad 0..15
  const int cs  = bid >> 5;              // col-slice: 32 h-cols
  const int gidx = dir*16 + bq;          // group 0..31 (8 cs-blocks each, same XCD)
  const float*  __restrict__ g    = gcur + (size_t)dir * CROWS * G4_;
  const __half* __restrict__ wsrc = wT16 + (size_t)dir * (G4_*H_);
  const int hoff = dir ? H_ : 0;

  // stage fp16 weight slice: cols [cs*128, +128) x 256 k
  for (int it = 0; it < 32; ++it) {
    const int idx = tid + (it << 8);     // 0..8191
    const int lc = idx >> 6;             // 0..127
    const int k0 = (idx & 63) << 2;      // 0..252
    const uint2 u = *(const uint2*)&wsrc[(size_t)(cs*128 + lc)*256 + k0];
    *(uint2*)&sm.r.w[lc][k0] = u;
  }
  for (int it = 0; it < 4; ++it) {
    const int idx = tid + (it << 8);
    const int b = idx >> 8, col = idx & 255;
    sm.r.hp[b][col] = first ? 0.f : stH[((size_t)(dir*B_ + bq*4 + b))*H_ + col];
  }
  const int ab  = tid >> 5;              // activation batch (tid<128)
  const int ajl = tid & 31;              // activation h-col-local
  float creg = 0.f;
  if (!first && tid < 128)
    creg = stC[((size_t)(dir*B_ + bq*4 + ab))*H_ + cs*32 + ajl];
  __syncthreads();

  const int ks = tid >> 7;               // k-half 0..1
  const int lc = tid & 127;              // gate-col-local
  const int gi = lc & 3, jl = lc >> 2;
  const int kb = ks << 7;
  const int gb0  = tid >> 7;             // gate prefetch mapping
  const int grem = tid & 127;
  const int ggi = grem >> 5, gjl = grem & 31;
  const size_t gcol = (size_t)ggi*256 + cs*32 + gjl;

  for (int sl = 0; sl < C_; ++sl) {
    const int t  = dir ? (t0b + C_-1-sl) : (t0f + sl);
    const int tl = dir ? (C_-1-sl) : sl;
    const float gv0 = g[(size_t)((bq*4 + gb0    )*C_ + tl)*G4_ + gcol];
    const float gv1 = g[(size_t)((bq*4 + gb0 + 2)*C_ + tl)*G4_ + gcol];

    float acc0=0.f, acc1=0.f, acc2=0.f, acc3=0.f;
    #pragma unroll 8
    for (int kq = 0; kq < 32; ++kq) {
      const int k0 = kb + (kq << 2);
      const uint2 u = *(const uint2*)&sm.r.w[lc][k0];
      __half2 p01, p23;
      *(unsigned*)&p01 = u.x; *(unsigned*)&p23 = u.y;
      const float2 f01 = __half22float2(p01);
      const float2 f23 = __half22float2(p23);
      const float4 h0 = *(const float4*)&sm.r.hp[0][k0];
      const float4 h1 = *(const float4*)&sm.r.hp[1][k0];
      const float4 h2 = *(const float4*)&sm.r.hp[2][k0];
      const float4 h3 = *(const float4*)&sm.r.hp[3][k0];
      acc0 = fmaf(f01.x,h0.x,fmaf(f01.y,h0.y,fmaf(f23.x,h0.z,fmaf(f23.y,h0.w,acc0))));
      acc1 = fmaf(f01.x,h1.x,fmaf(f01.y,h1.y,fmaf(f23.x,h1.z,fmaf(f23.y,h1.w,acc1))));
      acc2 = fmaf(f01.x,h2.x,fmaf(f01.y,h2.y,fmaf(f23.x,h2.z,fmaf(f23.y,h2.w,acc2))));
      acc3 = fmaf(f01.x,h3.x,fmaf(f01.y,h3.y,fmaf(f23.x,h3.z,fmaf(f23.y,h3.w,acc3))));
    }
    sm.r.psum[ks][gi][jl][0]=acc0; sm.r.psum[ks][gi][jl][1]=acc1;
    sm.r.psum[ks][gi][jl][2]=acc2; sm.r.psum[ks][gi][jl][3]=acc3;
    sm.r.gbuf[gb0    ][ggi][gjl] = gv0;
    sm.r.gbuf[gb0 + 2][ggi][gjl] = gv1;
    __syncthreads();

    const int e = ebase + sl;
    const int par = e & 1;
    const unsigned tag = (unsigned)(e + 1);
    if (tid < 128) {
      const float pre0 = sm.r.gbuf[ab][0][ajl] + sm.r.psum[0][0][ajl][ab] + sm.r.psum[1][0][ajl][ab];
      const float pre1 = sm.r.gbuf[ab][1][ajl] + sm.r.psum[0][1][ajl][ab] + sm.r.psum[1][1][ajl][ab];
      const float pre2 = sm.r.gbuf[ab][2][ajl] + sm.r.psum[0][2][ajl][ab] + sm.r.psum[1][2][ajl][ab];
      const float pre3 = sm.r.gbuf[ab][3][ajl] + sm.r.psum[0][3][ajl][ab] + sm.r.psum[1][3][ajl][ab];
      const float iv = sigf(pre0), fv = sigf(pre1);
      const float zv = tanhf(pre2), ov = sigf(pre3);
      creg = fv*creg + iv*zv;
      const float hn = ov * tanhf(creg);
      h_bi[((size_t)((bq*4+ab)*S_ + t))*(2*H_) + hoff + cs*32 + ajl] = hn;
      if (sl < C_-1) {
        const unsigned long long pk =
            ((unsigned long long)tag << 32) | (unsigned long long)__float_as_uint(hn);
        __hip_atomic_store(&hx[(((size_t)par*32 + gidx)*4 + ab)*256 + cs*32 + ajl], pk,
                           __ATOMIC_RELAXED, __HIP_MEMORY_SCOPE_AGENT);
      } else {
        stH[((size_t)(dir*B_ + bq*4 + ab))*H_ + cs*32 + ajl] = hn;
        stC[((size_t)(dir*B_ + bq*4 + ab))*H_ + cs*32 + ajl] = creg;
      }
    }
    if (sl == C_-1) break;

    // fence-free gather: poll u64 (tag|value), 4 in flight per thread
    {
      const unsigned long long* hb = &hx[((size_t)par*32 + gidx) << 10];
      float r0,r1,r2,r3;
      bool d0=false,d1=false,d2=false,d3=false;
      for (;;) {
        if (!d0) { unsigned long long v = __hip_atomic_load(hb + tid,       __ATOMIC_RELAXED, __HIP_MEMORY_SCOPE_AGENT);
                   if ((unsigned)(v>>32) == tag) { r0 = __uint_as_float((unsigned)v); d0 = true; } }
        if (!d1) { unsigned long long v = __hip_atomic_load(hb + 256 + tid, __ATOMIC_RELAXED, __HIP_MEMORY_SCOPE_AGENT);
                   if ((unsigned)(v>>32) == tag) { r1 = __uint_as_float((unsigned)v); d1 = true; } }
        if (!d2) { unsigned long long v = __hip_atomic_load(hb + 512 + tid, __ATOMIC_RELAXED, __HIP_MEMORY_SCOPE_AGENT);
                   if ((unsigned)(v>>32) == tag) { r2 = __uint_as_float((unsigned)v); d2 = true; } }
        if (!d3) { unsigned long long v = __hip_atomic_load(hb + 768 + tid, __ATOMIC_RELAXED, __HIP_MEMORY_SCOPE_AGENT);
                   if ((unsigned)(v>>32) == tag) { r3 = __uint_as_float((unsigned)v); d3 = true; } }
        if (d0 && d1 && d2 && d3) break;
        __builtin_amdgcn_s_sleep(1);
      }
      sm.r.hp[0][tid] = r0; sm.r.hp[1][tid] = r1;
      sm.r.hp[2][tid] = r2; sm.r.hp[3][tid] = r3;
    }
    __syncthreads();
  }
}

__global__ __launch_bounds__(256) void gold_kernel(
    const int* __restrict__ labels, const int* __restrict__ maskp,
    const float* __restrict__ emitp, const float* __restrict__ trans, double* __restrict__ gold) {
  const int b = blockIdx.x; const int tid = threadIdx.x;
  double acc = 0.0; int len = 0;
  for (int t = tid; t < S_; t += 256) {
    int mk = maskp[b*S_ + t];
    len += mk;
    if (mk) {
      int lab  = labels[b*S_ + t];
      int prev = (t==0) ? START_ : labels[b*S_ + t - 1];
      acc += (double)trans[prev*T_ + lab] + (double)emitp[((size_t)b*S_ + t)*T_ + lab];
    }
  }
  __shared__ double sacc[256]; __shared__ int slen[256];
  sacc[tid]=acc; slen[tid]=len; __syncthreads();
  for (int s=128; s>0; s>>=1){ if (tid<s){ sacc[tid]+=sacc[tid+s]; slen[tid]+=slen[tid+s]; } __syncthreads(); }
  if (tid==0){
    int L = slen[0];
    int last = labels[b*S_ + L - 1];
    gold[b] = sacc[0] + (double)trans[last*T_ + STOP_];
  }
}

// Register-resident CRF-forward (role 0) + Viterbi (role 1). One wave per (batch, role).
__global__ __launch_bounds__(64) void crf_vit_kernel(
    const float* __restrict__ emitp, const float* __restrict__ trans,
    const int* __restrict__ maskp, double* __restrict__ fwd, float* __restrict__ out_tags) {
  const int b = blockIdx.x;
  const int role = blockIdx.y;
  const int lane = threadIdx.x;
  const int k = lane & 31, p = lane >> 5;
  const int kk = (k < T_) ? k : 0;

  __shared__ float trs[T_*T_];
  for (int i = lane; i < T_*T_; i += 64) trs[i] = trans[i];
  __syncthreads();

  // preload this lane's trans column: sources j = p*11+u -> target kk
  float trreg[11];
  #pragma unroll
  for (int u = 0; u < 11; ++u) trreg[u] = trs[(p*11 + u)*T_ + kk];

  if (role == 0) {
    double al_r = 0.0;
    if (lane < T_) al_r = (double)emitp[(size_t)b*S_*T_ + lane] + (double)trs[START_*T_ + lane];
    float ce = emitp[((size_t)b*S_ + 1)*T_ + kk];
    int   cm = maskp[b*S_ + 1];
    for (int t = 1; t < S_; ++t) {
      float ne = 0.f; int nm = 0;
      if (t+1 < S_) { ne = emitp[((size_t)b*S_ + t + 1)*T_ + kk]; nm = maskp[b*S_ + t + 1]; }
      double tj[11];
      #pragma unroll
      for (int u = 0; u < 11; ++u)
        tj[u] = __shfl(al_r, p*11 + u) + (double)trreg[u];
      double m = tj[0];
      #pragma unroll
      for (int u = 1; u < 11; ++u) m = fmax(m, tj[u]);
      m = fmax(m, __shfl_xor(m, 32));
      float s = 0.f;
      #pragma unroll
      for (int u = 0; u < 11; ++u) s += __expf((float)(tj[u] - m));
      s += __shfl_xor(s, 32);
      const double nv = m + (double)__logf(s) + (double)ce;
      if (cm && lane < T_) al_r = nv;
      ce = ne; cm = nm;
    }
    if (lane < T_) al_r += (double)trs[lane*T_ + STOP_];
    // wave-reduce logsumexp over lanes 0..21
    double mx = (lane < T_) ? al_r : -1e300;
    #pragma unroll
    for (int o = 32; o > 0; o >>= 1) mx = fmax(mx, __shfl_xor(mx, o));
    double sv = (lane < T_) ? exp(al_r - mx) : 0.0;
    #pragma unroll
    for (int o = 32; o > 0; o >>= 1) sv += __shfl_xor(sv, o);
    if (lane == 0) fwd[b] = mx + log(sv);
  } else {
    __shared__ unsigned char bp[S_][T_];
    __shared__ int msk[S_];
    double dl_r = 0.0;
    if (lane < T_) dl_r = (double)emitp[(size_t)b*S_*T_ + lane] + (double)trs[START_*T_ + lane];
    if (lane == 0) msk[0] = maskp[b*S_];
    float ce = emitp[((size_t)b*S_ + 1)*T_ + kk];
    int   cm = maskp[b*S_ + 1];
    for (int t = 1; t < S_; ++t) {
      float ne = 0.f; int nm = 0;
      if (t+1 < S_) { ne = emitp[((size_t)b*S_ + t + 1)*T_ + kk]; nm = maskp[b*S_ + t + 1]; }
      double best = __shfl(dl_r, p*11) + (double)trreg[0];
      int arg = p*11;
      #pragma unroll
      for (int u = 1; u < 11; ++u) {
        const double sc = __shfl(dl_r, p*11 + u) + (double)trreg[u];
        if (sc > best) { best = sc; arg = p*11 + u; }
      }
      const double ob = __shfl_xor(best, 32);
      const int    oa = __shfl_xor(arg, 32);
      if (p == 0 && ob > best) { best = ob; arg = oa; }   // strict >: lower j wins ties
      if (p == 0 && k < T_) {
        if (cm) { dl_r = best + (double)ce; bp[t][k] = (unsigned char)arg; }
        else    { bp[t][k] = (unsigned char)k; }
      }
      if (lane == 0) msk[t] = cm;
      ce = ne; cm = nm;
    }
    __syncthreads();
    // wave-uniform final argmax over j=0..21 (lowest j wins ties), all lanes active
    double sc = (lane < T_) ? dl_r + (double)trs[lane*T_ + STOP_] : -1e300;
    int cur = (lane < T_) ? lane : 0x7fffffff;
    #pragma unroll
    for (int o = 32; o > 0; o >>= 1) {
      const double osc = __shfl_xor(sc, o);
      const int    oid = __shfl_xor(cur, o);
      if (osc > sc || (osc == sc && oid < cur)) { sc = osc; cur = oid; }
    }
    if (lane == 0) {
      for (int t = S_-1; ; --t) {
        out_tags[b*S_ + t] = (float)(cur * msk[t]);
        if (t == 0) break;
        cur = bp[t][cur];
      }
    }
  }
}

__global__ void finalize_kernel(const double* __restrict__ fwd, const double* __restrict__ gold, float* __restrict__ out){
  if (threadIdx.x == 0 && blockIdx.x == 0) {
    double s = 0.0, g = 0.0;
    for (int b = 0; b < B_; ++b) { s += fwd[b]; g += gold[b]; }
    out[0] = (float)((s - g) / (double)B_);
  }
}

extern "C" void kernel_launch(void* const* d_in, const int* in_sizes, int n_in,
                              void* d_out, int out_size, void* d_ws, size_t ws_size,
                              hipStream_t stream) {
  const int*   word   = (const int*)d_in[0];
  const int*   maskp  = (const int*)d_in[1];
  const int*   labels = (const int*)d_in[2];
  const float* emb    = (const float*)d_in[3];
  const float* w_ih_f = (const float*)d_in[4];
  const float* w_hh_f = (const float*)d_in[5];
  const float* b_f    = (const float*)d_in[6];
  const float* w_ih_b = (const float*)d_in[7];
  const float* w_hh_b = (const float*)d_in[8];
  const float* b_b    = (const float*)d_in[9];
  const float* hw_W   = (const float*)d_in[10];
  const float* hw_b   = (const float*)d_in[11];
  const float* out_W  = (const float*)d_in[12];
  const float* out_b  = (const float*)d_in[13];
  const float* trans  = (const float*)d_in[14];
  float* out = (float*)d_out;

  // workspace layout (~88.6 MB)
  float* h_bi  = (float*)d_ws;                          // [32768,512] -> h2 in place
  float* buf0  = h_bi + 16777216ULL;                    // [2,1024,1024] gates ping
  float* buf1  = buf0 + 2097152ULL;                     // [2,1024,1024] gates pong
  __half* wT16 = (__half*)(buf1 + 2097152ULL);          // [2][1024 col][256 k] fp16
  float* emitp = (float*)(wT16 + 524288ULL);            // [32768,22]
  float* stH   = emitp + 720896ULL;                     // [2,64,256]
  float* stC   = stH + 32768ULL;                        // [2,64,256]
  unsigned long long* hx = (unsigned long long*)(stC + 32768ULL);  // [2 par][32 g][4 b][256]
  double* fwdp = (double*)(hx + 65536ULL);              // [64]
  double* goldp = fwdp + 64;                            // [64]

  hipMemsetAsync(hx, 0, 65536ULL * 8, stream);          // clear tags (replay safety)

  wtr16_kernel<<<1024, 256, 0, stream>>>(w_hh_f, wT16);
  wtr16_kernel<<<1024, 256, 0, stream>>>(w_hh_b, wT16 + 262144ULL);

  // chunk 0 gates -> buf0
  gemm_gates<<<dim3(CROWS/64, 16, 2), 256, 0, stream>>>(
      word, maskp, emb, w_ih_f, b_f, w_ih_b, b_b, buf0, 0, S_ - C_);

  // fused recurrence + next-chunk gates
  for (int i = 0; i < NCH; ++i) {
    const int t0f = i * C_;
    const int t0b = S_ - (i + 1) * C_;
    const int n0f = (i < NCH-1) ? (i + 1) * C_ : -1;
    const int n0b = S_ - (i + 2) * C_;
    float* gcur = (i & 1) ? buf1 : buf0;
    float* gnext = (i & 1) ? buf0 : buf1;
    lstm_mega<<<512, 256, 0, stream>>>(
        gcur, gnext, word, maskp, emb, w_ih_f, b_f, w_ih_b, b_b,
        wT16, h_bi, stH, stC, hx, t0f, t0b, n0f, n0b, i*(C_-1), (i == 0) ? 1 : 0);
  }

  // full-width fused highway (in place on h_bi, no proj buffer)
  gemm_hw_full<<<M_/32, 256, 0, stream>>>(h_bi, hw_W, hw_b);

  // emissions
  gemm_tiled<<<dim3(M_/64, 1), 256, 0, stream>>>(
      h_bi, nullptr, nullptr, nullptr, out_W, out_b, emitp, 2*H_, T_, 0, 0, C_);

  // CRF
  gold_kernel<<<64, 256, 0, stream>>>(labels, maskp, emitp, trans, goldp);
  crf_vit_kernel<<<dim3(64, 2), 64, 0, stream>>>(emitp, trans, maskp, fwdp, out + 1);
  finalize_kernel<<<1, 64, 0, stream>>>(fwdp, goldp, out);
}